// Round 6
// baseline (409.521 us; speedup 1.0000x reference)
//
#include <hip/hip_runtime.h>
#include <hip/hip_bf16.h>

// Attn: energies = out_state @ (history @ W.T).T ; softmax rows.
// (bias dropped: os.b is constant per softmax row -> cancels in softmax.)
// S2=S1=4096, N=1024. fp32 in/out. No fp32 MFMA on CDNA4 -> bf16 hi/lo 3-term
// compensated GEMM folded into K: A'=[Ah,Al,Ah], B'=[Bh,Bh,Bl], K=3072.
// R2: dbuf + global_load_lds prefetch.  R4 (reverted): reg-staged spill.
// R5: XCD swizzle (neutral, kept).
// R6: THE RESTRUCTURE. 3-deep LDS pipeline, raw s_barrier (no fence) +
// per-wave s_waitcnt vmcnt(G) -- never a vmcnt(0) drain in steady state.
// Iter k: wait group k (issued 2 iters ago) | s_barrier | issue group k+2 |
// compute k. Breaks the barrier-drain convoy that pinned MfmaUtil at 19.6%.

typedef __bf16 bf16x8 __attribute__((ext_vector_type(8)));
typedef float f32x4 __attribute__((ext_vector_type(4)));
typedef unsigned short u16x4 __attribute__((ext_vector_type(4)));

__device__ __forceinline__ unsigned short f2bf(float x) {
  unsigned int u = __float_as_uint(x);
  u += 0x7fffu + ((u >> 16) & 1u);   // RNE
  return (unsigned short)(u >> 16);
}
__device__ __forceinline__ float bf2f(unsigned short h) {
  return __uint_as_float(((unsigned int)h) << 16);
}

__device__ __forceinline__ void async_copy_16(void* lds, const void* gsrc) {
  __builtin_amdgcn_global_load_lds(
      (const __attribute__((address_space(1))) void*)gsrc,
      (__attribute__((address_space(3))) void*)lds, 16, 0, 0);
}

// Split fp32 X[rows x 1024] -> Y[rows x 3072] bf16.
// bside=0 (A-operand): [hi | lo | hi]   bside=1 (B-operand): [hi | hi | lo]
__global__ __launch_bounds__(256)
void split_kernel(const float* __restrict__ X, unsigned short* __restrict__ Y, int bside) {
  const size_t row = blockIdx.x;
  const int c4 = threadIdx.x;                       // 256 threads x 4 cols = 1024
  float4 x = ((const float4*)(X + row * 1024))[c4];
  float xs[4] = {x.x, x.y, x.z, x.w};
  u16x4 h, l;
#pragma unroll
  for (int i = 0; i < 4; ++i) {
    unsigned short hh = f2bf(xs[i]);
    h[i] = hh;
    l[i] = f2bf(xs[i] - bf2f(hh));
  }
  u16x4* y0 = (u16x4*)(Y + row * 3072 + (size_t)c4 * 4);  // 256 u16x4 per 1024 cols
  if (bside) { y0[0] = h; y0[256] = h; y0[512] = l; }
  else       { y0[0] = h; y0[256] = l; y0[512] = h; }
}

// C[M,N] = A[M,K] . B[N,K]^T, bf16 in, fp32 acc. BM=128, 256 threads, wave grid
// 2x2 (wave tile 64 x BN/2). Fragment-ordered LDS: for 16-row group g, k-seg s
// (8 bf16), row r: byte offset = g*1024 + s*256 + r*16 == group base + lane*16
// (lane = s*16+r) -> matches global_load_lds wave-uniform-base+lane*16 and is
// conflict-free for ds_read_b128 frag loads.
// 3-deep pipeline, one bare s_barrier per iter, vmcnt(G) steady-state waits.
// EPI=0: store fp32 C. EPI=1: write [hi|hi|lo] split of acc into P2.
template <int BN, int EPI, int GM, int GN, int RM, int RN>
__global__ __launch_bounds__(256)
void gemm_bt(const unsigned short* __restrict__ A,
             const unsigned short* __restrict__ B,
             float* __restrict__ C,
             unsigned short* __restrict__ P2,
             int M, int N, int K) {
  constexpr int BM = 128;
  constexpr int NT = BN / 32;            // n-frags per wave
  constexpr int NB = BN / 64;            // B staging chunks per wave
  constexpr int G = 2 + NB;              // vmem loads per wave per iter
  // s_waitcnt imm: lgkmcnt=15 (no wait), expcnt=7 (no wait), vmcnt in [3:0]
  constexpr int WAIT_G = 0x0F70 | G;
  constexpr int WAIT_0 = 0x0F70;
  __shared__ unsigned short As[3][BM * 32];
  __shared__ unsigned short Bs[3][BN * 32];

  const int tid = threadIdx.x;
  const int w = tid >> 6;
  const int lane = tid & 63;
  const int wm = w >> 1, wn = w & 1;
  const int lr = lane & 15;              // m/n index within 16-tile
  const int ls = lane >> 4;              // k-segment (8 bf16 each)

  // XCD-aware super-tile swizzle
  const int id = blockIdx.x;
  const int xcd = id & 7;
  const int j = id >> 3;
  const int bm = ((xcd % (GM / RM)) * RM + (j % RM)) * BM;
  const int bn = ((xcd / (GM / RM)) * RN + (j / RM)) * BN;

  // staging source pointers (hoisted; advance by k-offset each issue)
  const unsigned short* pa0 = A + (size_t)(bm + (w * 2 + 0) * 16 + lr) * K + ls * 8;
  const unsigned short* pa1 = A + (size_t)(bm + (w * 2 + 1) * 16 + lr) * K + ls * 8;
  const unsigned short* pb[NB];
#pragma unroll
  for (int c = 0; c < NB; ++c)
    pb[c] = B + (size_t)(bn + (w * NB + c) * 16 + lr) * K + ls * 8;

  f32x4 acc[4][NT] = {};

  const int NIT = K >> 5;                // K/32 iterations

  // issue one staging group (G loads) for iteration kk into buffer buf
  auto stage = [&](int buf, int kk) {
    const int koff = kk * 32;
    async_copy_16(&As[buf][(w * 2 + 0) * 512], pa0 + koff);
    async_copy_16(&As[buf][(w * 2 + 1) * 512], pa1 + koff);
#pragma unroll
    for (int c = 0; c < NB; ++c)
      async_copy_16(&Bs[buf][(w * NB + c) * 512], pb[c] + koff);
  };

  auto compute = [&](int buf) {
    bf16x8 af[4], bfr[NT];
#pragma unroll
    for (int mt = 0; mt < 4; ++mt)
      af[mt] = *(const bf16x8*)&As[buf][(wm * 4 + mt) * 512 + ls * 128 + lr * 8];
#pragma unroll
    for (int nt = 0; nt < NT; ++nt)
      bfr[nt] = *(const bf16x8*)&Bs[buf][(wn * NT + nt) * 512 + ls * 128 + lr * 8];
#pragma unroll
    for (int mt = 0; mt < 4; ++mt)
#pragma unroll
      for (int nt = 0; nt < NT; ++nt)
        acc[mt][nt] = __builtin_amdgcn_mfma_f32_16x16x32_bf16(af[mt], bfr[nt], acc[mt][nt], 0, 0, 0);
  };

  // prologue: issue groups 0 and 1 (2G outstanding)
  stage(0, 0);
  stage(1, 1);

  int bc = 0;        // compute buffer for iter k
  for (int k = 0; k < NIT - 1; ++k) {
    // retire group k (oldest G of the <=2G outstanding) -- issued 2 iters ago
    __builtin_amdgcn_s_waitcnt(WAIT_G);
    __builtin_amdgcn_s_barrier();          // bare barrier: NO vmcnt(0) fence
    if (k + 2 < NIT) {
      int bp = bc + 2; if (bp >= 3) bp -= 3;
      stage(bp, k + 2);                    // safe: all waves past compute k-1
    }
    compute(bc);
    if (++bc == 3) bc = 0;
  }
  // final iteration: drain remaining group
  __builtin_amdgcn_s_waitcnt(WAIT_0);
  __builtin_amdgcn_s_barrier();
  compute(bc);

  // Epilogue. C/D layout (m89/m91): col(n) = lane&15, row(m) = (lane>>4)*4 + reg.
  const int cm0 = bm + wm * 64;
  const int cn0 = bn + wn * (BN / 2);
#pragma unroll
  for (int mt = 0; mt < 4; ++mt) {
#pragma unroll
    for (int nt = 0; nt < NT; ++nt) {
      const int col = cn0 + nt * 16 + lr;
      const int row0 = cm0 + mt * 16 + ls * 4;
      if constexpr (EPI == 0) {
#pragma unroll
        for (int r = 0; r < 4; ++r)
          C[(size_t)(row0 + r) * N + col] = acc[mt][nt][r];
      } else {
#pragma unroll
        for (int r = 0; r < 4; ++r) {
          const float p = acc[mt][nt][r];
          const unsigned short h = f2bf(p);
          const unsigned short l = f2bf(p - bf2f(h));
          const size_t base = (size_t)(row0 + r) * 3072 + col;
          P2[base] = h;
          P2[base + 1024] = h;
          P2[base + 2048] = l;
        }
      }
    }
  }
}

// In-place row softmax, N=4096, one block per row, 16 floats/thread in regs.
__global__ __launch_bounds__(256)
void softmax_inplace(float* __restrict__ C, int N) {
  float4* r4 = (float4*)(C + (size_t)blockIdx.x * N);
  const int t = threadIdx.x;
  float4 v[4];
  float mx = -3.0e38f;
#pragma unroll
  for (int i = 0; i < 4; ++i) {
    v[i] = r4[t + i * 256];
    mx = fmaxf(mx, fmaxf(fmaxf(v[i].x, v[i].y), fmaxf(v[i].z, v[i].w)));
  }
#pragma unroll
  for (int o = 32; o; o >>= 1) mx = fmaxf(mx, __shfl_xor(mx, o, 64));
  __shared__ float smax[4], ssum[4];
  const int w = t >> 6;
  if ((t & 63) == 0) smax[w] = mx;
  __syncthreads();
  mx = fmaxf(fmaxf(smax[0], smax[1]), fmaxf(smax[2], smax[3]));
  float s = 0.f;
#pragma unroll
  for (int i = 0; i < 4; ++i) {
    v[i].x = __expf(v[i].x - mx);
    v[i].y = __expf(v[i].y - mx);
    v[i].z = __expf(v[i].z - mx);
    v[i].w = __expf(v[i].w - mx);
    s += (v[i].x + v[i].y) + (v[i].z + v[i].w);
  }
#pragma unroll
  for (int o = 32; o; o >>= 1) s += __shfl_xor(s, o, 64);
  if ((t & 63) == 0) ssum[w] = s;
  __syncthreads();
  const float inv = 1.0f / (ssum[0] + ssum[1] + ssum[2] + ssum[3]);
#pragma unroll
  for (int i = 0; i < 4; ++i) {
    v[i].x *= inv; v[i].y *= inv; v[i].z *= inv; v[i].w *= inv;
    r4[t + i * 256] = v[i];
  }
}

extern "C" void kernel_launch(void* const* d_in, const int* in_sizes, int n_in,
                              void* d_out, int out_size, void* d_ws, size_t ws_size,
                              hipStream_t stream) {
  const float* out_state = (const float*)d_in[0];  // [4096,1024]
  const float* history   = (const float*)d_in[1];  // [4096,1024]
  const float* W         = (const float*)d_in[2];  // [1024,1024]
  float* out = (float*)d_out;                      // [4096,4096]

  unsigned short* H2 = (unsigned short*)d_ws;                 // 4096x3072
  unsigned short* W2 = H2 + (size_t)4096 * 3072;              // 1024x3072
  unsigned short* A2 = W2 + (size_t)1024 * 3072;              // 4096x3072
  unsigned short* P2 = A2 + (size_t)4096 * 3072;              // 4096x3072

  split_kernel<<<4096, 256, 0, stream>>>(history, H2, 0);
  split_kernel<<<1024, 256, 0, stream>>>(W, W2, 1);
  split_kernel<<<4096, 256, 0, stream>>>(out_state, A2, 0);

  // proj -> P2 split. M=4096 (32 tiles), N=1024 (16 tiles of 64), K=3072.
  // 512 blocks; per-XCD region 8x8 tiles.
  gemm_bt<64, 1, 32, 16, 8, 8><<<512, 256, 0, stream>>>(
      H2, W2, nullptr, P2, 4096, 1024, 3072);

  // energies -> d_out. M=N=4096 (32x32 tiles of 128), K=3072.
  // 1024 blocks; per-XCD region 16x8 tiles.
  gemm_bt<128, 0, 32, 32, 16, 8><<<1024, 256, 0, stream>>>(
      A2, P2, out, nullptr, 4096, 4096, 3072);

  softmax_inplace<<<4096, 256, 0, stream>>>(out, 4096);
}

// Round 7
// 335.701 us; speedup vs baseline: 1.2199x; 1.2199x over previous
//
#include <hip/hip_runtime.h>
#include <hip/hip_bf16.h>

// Attn: energies = out_state @ (history @ W.T).T ; softmax rows.
// (bias dropped: os.b is constant per softmax row -> cancels in softmax.)
// S2=S1=4096, N=1024. fp32 in/out. No fp32 MFMA on CDNA4 -> bf16 hi/lo 3-term
// compensated GEMM folded into K: A'=[Ah,Al,Ah], B'=[Bh,Bh,Bl], K=3072.
// R2: dbuf + global_load_lds prefetch (kept).  R4: reg-staged spill (reverted).
// R5: XCD swizzle (neutral, kept).  R6: vmcnt pipeline (neutral, reverted).
// R7: MfmaUtil invariant at ~19% across 4 sync structures -> staging-bytes
// bound, not sync-bound. Raise arithmetic intensity: stage-2 tile 256x128
// (wave-tile 128x64, 85 FLOP/B vs 64), -25% staged bytes & barrier slots.

typedef __bf16 bf16x8 __attribute__((ext_vector_type(8)));
typedef float f32x4 __attribute__((ext_vector_type(4)));
typedef unsigned short u16x4 __attribute__((ext_vector_type(4)));

__device__ __forceinline__ unsigned short f2bf(float x) {
  unsigned int u = __float_as_uint(x);
  u += 0x7fffu + ((u >> 16) & 1u);   // RNE
  return (unsigned short)(u >> 16);
}
__device__ __forceinline__ float bf2f(unsigned short h) {
  return __uint_as_float(((unsigned int)h) << 16);
}

__device__ __forceinline__ void async_copy_16(void* lds, const void* gsrc) {
  __builtin_amdgcn_global_load_lds(
      (const __attribute__((address_space(1))) void*)gsrc,
      (__attribute__((address_space(3))) void*)lds, 16, 0, 0);
}

// Split fp32 X[rows x 1024] -> Y[rows x 3072] bf16.
// bside=0 (A-operand): [hi | lo | hi]   bside=1 (B-operand): [hi | hi | lo]
__global__ __launch_bounds__(256)
void split_kernel(const float* __restrict__ X, unsigned short* __restrict__ Y, int bside) {
  const size_t row = blockIdx.x;
  const int c4 = threadIdx.x;                       // 256 threads x 4 cols = 1024
  float4 x = ((const float4*)(X + row * 1024))[c4];
  float xs[4] = {x.x, x.y, x.z, x.w};
  u16x4 h, l;
#pragma unroll
  for (int i = 0; i < 4; ++i) {
    unsigned short hh = f2bf(xs[i]);
    h[i] = hh;
    l[i] = f2bf(xs[i] - bf2f(hh));
  }
  u16x4* y0 = (u16x4*)(Y + row * 3072 + (size_t)c4 * 4);  // 256 u16x4 per 1024 cols
  if (bside) { y0[0] = h; y0[256] = h; y0[512] = l; }
  else       { y0[0] = h; y0[256] = l; y0[512] = h; }
}

// C[M,N] = A[M,K] . B[N,K]^T, bf16 in, fp32 acc. 256 threads, wave grid 2x2,
// wave tile (BM/2) x (BN/2). Fragment-ordered LDS: 16-row group g, k-seg s
// (8 bf16), row r at byte g*1024 + s*256 + r*16 == group base + lane*16
// (lane = s*16+r) -> matches global_load_lds wave-uniform-base+lane*16; 2-way
// bank aliasing only (free) on ds_read_b128 frag loads.
// Double-buffered: iter = barrier (drains prev prefetch, publishes buf cur) ->
// issue DMA for kt+32 into buf^1 -> frag reads + MFMA on buf cur.
// EPI=0: store fp32 C. EPI=1: write [hi|hi|lo] split of acc into P2.
template <int BM, int BN, int EPI, int GM, int GN, int RM, int RN>
__global__ __launch_bounds__(256)
void gemm_bt(const unsigned short* __restrict__ A,
             const unsigned short* __restrict__ B,
             float* __restrict__ C,
             unsigned short* __restrict__ P2,
             int M, int N, int K) {
  constexpr int MT = BM / 32;            // m-frags per wave
  constexpr int NT = BN / 32;            // n-frags per wave
  constexpr int NA = BM / 64;            // A staging chunks per wave
  constexpr int NB = BN / 64;            // B staging chunks per wave
  __shared__ unsigned short As[2][BM * 32];
  __shared__ unsigned short Bs[2][BN * 32];

  const int tid = threadIdx.x;
  const int w = tid >> 6;
  const int lane = tid & 63;
  const int wm = w >> 1, wn = w & 1;
  const int lr = lane & 15;              // m/n index within 16-tile
  const int ls = lane >> 4;              // k-segment (8 bf16 each)

  // XCD-aware super-tile swizzle
  const int id = blockIdx.x;
  const int xcd = id & 7;
  const int j = id >> 3;
  const int bm = ((xcd % (GM / RM)) * RM + (j % RM)) * BM;
  const int bn = ((xcd / (GM / RM)) * RN + (j / RM)) * BN;

  // staging source pointers (hoisted; advance by kt each iter)
  const unsigned short* pa[NA];
#pragma unroll
  for (int c = 0; c < NA; ++c)
    pa[c] = A + (size_t)(bm + (w * NA + c) * 16 + lr) * K + ls * 8;
  const unsigned short* pb[NB];
#pragma unroll
  for (int c = 0; c < NB; ++c)
    pb[c] = B + (size_t)(bn + (w * NB + c) * 16 + lr) * K + ls * 8;

  f32x4 acc[MT][NT] = {};

  // prologue: stage kt=0 into buf 0
#pragma unroll
  for (int c = 0; c < NA; ++c)
    async_copy_16(&As[0][(w * NA + c) * 512], pa[c]);
#pragma unroll
  for (int c = 0; c < NB; ++c)
    async_copy_16(&Bs[0][(w * NB + c) * 512], pb[c]);

  int cur = 0;
  for (int kt = 0; kt < K; kt += 32) {
    __syncthreads();   // drains our DMAs (vmcnt 0) + publishes buf `cur`

    if (kt + 32 < K) {  // prefetch next K-slab into the other buffer
      const int nxt = cur ^ 1;
#pragma unroll
      for (int c = 0; c < NA; ++c)
        async_copy_16(&As[nxt][(w * NA + c) * 512], pa[c] + kt + 32);
#pragma unroll
      for (int c = 0; c < NB; ++c)
        async_copy_16(&Bs[nxt][(w * NB + c) * 512], pb[c] + kt + 32);
    }

    bf16x8 af[MT], bfr[NT];
#pragma unroll
    for (int mt = 0; mt < MT; ++mt)
      af[mt] = *(const bf16x8*)&As[cur][(wm * MT + mt) * 512 + ls * 128 + lr * 8];
#pragma unroll
    for (int nt = 0; nt < NT; ++nt)
      bfr[nt] = *(const bf16x8*)&Bs[cur][(wn * NT + nt) * 512 + ls * 128 + lr * 8];

#pragma unroll
    for (int mt = 0; mt < MT; ++mt)
#pragma unroll
      for (int nt = 0; nt < NT; ++nt)
        acc[mt][nt] = __builtin_amdgcn_mfma_f32_16x16x32_bf16(af[mt], bfr[nt], acc[mt][nt], 0, 0, 0);

    cur ^= 1;
  }

  // Epilogue. C/D layout (m89/m91): col(n) = lane&15, row(m) = (lane>>4)*4 + reg.
  const int cm0 = bm + wm * (BM / 2);
  const int cn0 = bn + wn * (BN / 2);
#pragma unroll
  for (int mt = 0; mt < MT; ++mt) {
#pragma unroll
    for (int nt = 0; nt < NT; ++nt) {
      const int col = cn0 + nt * 16 + lr;
      const int row0 = cm0 + mt * 16 + ls * 4;
      if constexpr (EPI == 0) {
#pragma unroll
        for (int r = 0; r < 4; ++r)
          C[(size_t)(row0 + r) * N + col] = acc[mt][nt][r];
      } else {
#pragma unroll
        for (int r = 0; r < 4; ++r) {
          const float p = acc[mt][nt][r];
          const unsigned short h = f2bf(p);
          const unsigned short l = f2bf(p - bf2f(h));
          const size_t base = (size_t)(row0 + r) * 3072 + col;
          P2[base] = h;
          P2[base + 1024] = h;
          P2[base + 2048] = l;
        }
      }
    }
  }
}

// In-place row softmax, N=4096, one block per row, 16 floats/thread in regs.
__global__ __launch_bounds__(256)
void softmax_inplace(float* __restrict__ C, int N) {
  float4* r4 = (float4*)(C + (size_t)blockIdx.x * N);
  const int t = threadIdx.x;
  float4 v[4];
  float mx = -3.0e38f;
#pragma unroll
  for (int i = 0; i < 4; ++i) {
    v[i] = r4[t + i * 256];
    mx = fmaxf(mx, fmaxf(fmaxf(v[i].x, v[i].y), fmaxf(v[i].z, v[i].w)));
  }
#pragma unroll
  for (int o = 32; o; o >>= 1) mx = fmaxf(mx, __shfl_xor(mx, o, 64));
  __shared__ float smax[4], ssum[4];
  const int w = t >> 6;
  if ((t & 63) == 0) smax[w] = mx;
  __syncthreads();
  mx = fmaxf(fmaxf(smax[0], smax[1]), fmaxf(smax[2], smax[3]));
  float s = 0.f;
#pragma unroll
  for (int i = 0; i < 4; ++i) {
    v[i].x = __expf(v[i].x - mx);
    v[i].y = __expf(v[i].y - mx);
    v[i].z = __expf(v[i].z - mx);
    v[i].w = __expf(v[i].w - mx);
    s += (v[i].x + v[i].y) + (v[i].z + v[i].w);
  }
#pragma unroll
  for (int o = 32; o; o >>= 1) s += __shfl_xor(s, o, 64);
  if ((t & 63) == 0) ssum[w] = s;
  __syncthreads();
  const float inv = 1.0f / (ssum[0] + ssum[1] + ssum[2] + ssum[3]);
#pragma unroll
  for (int i = 0; i < 4; ++i) {
    v[i].x *= inv; v[i].y *= inv; v[i].z *= inv; v[i].w *= inv;
    r4[t + i * 256] = v[i];
  }
}

extern "C" void kernel_launch(void* const* d_in, const int* in_sizes, int n_in,
                              void* d_out, int out_size, void* d_ws, size_t ws_size,
                              hipStream_t stream) {
  const float* out_state = (const float*)d_in[0];  // [4096,1024]
  const float* history   = (const float*)d_in[1];  // [4096,1024]
  const float* W         = (const float*)d_in[2];  // [1024,1024]
  float* out = (float*)d_out;                      // [4096,4096]

  unsigned short* H2 = (unsigned short*)d_ws;                 // 4096x3072
  unsigned short* W2 = H2 + (size_t)4096 * 3072;              // 1024x3072
  unsigned short* A2 = W2 + (size_t)1024 * 3072;              // 4096x3072
  unsigned short* P2 = A2 + (size_t)4096 * 3072;              // 4096x3072

  split_kernel<<<4096, 256, 0, stream>>>(history, H2, 0);
  split_kernel<<<1024, 256, 0, stream>>>(W, W2, 1);
  split_kernel<<<4096, 256, 0, stream>>>(out_state, A2, 0);

  // proj -> P2 split. BM=128, BN=64: M 32 tiles, N 16 tiles -> 512 blocks;
  // per-XCD region 8x8 tiles.
  gemm_bt<128, 64, 1, 32, 16, 8, 8><<<512, 256, 0, stream>>>(
      H2, W2, nullptr, P2, 4096, 1024, 3072);

  // energies -> d_out. BM=256, BN=128: 16x32 tiles -> 512 blocks (2/CU);
  // per-XCD region 8x8 tiles (regions 2x4).
  gemm_bt<256, 128, 0, 16, 32, 8, 8><<<512, 256, 0, stream>>>(
      A2, P2, out, nullptr, 4096, 4096, 3072);

  softmax_inplace<<<4096, 256, 0, stream>>>(out, 4096);
}